// Round 8
// baseline (84.268 us; speedup 1.0000x reference)
//
#include <hip/hip_runtime.h>
#include <math.h>

#define NCOLS 8
#define ENUM 12
#define EDIM 16
#define VPAD 20          // padded word stride: (20v+d)%32 spreads banks, <=2-way conflict (free)
#define TABSZ (NCOLS * ENUM * VPAD)
#define NPAIR 28
#define TPB 256
#define EPB (TPB / 2)    // 2 threads per element (dim-split) -> 128 elems/block, 2048 blocks

// triu_indices(8, k=1) order
__device__ __constant__ const int kPI[NPAIR] = {0,0,0,0,0,0,0, 1,1,1,1,1,1, 2,2,2,2,2, 3,3,3,3, 4,4,4, 5,5, 6};
__device__ __constant__ const int kPJ[NPAIR] = {1,2,3,4,5,6,7, 2,3,4,5,6,7, 3,4,5,6,7, 4,5,6,7, 5,6,7, 6,7, 7};

// 8 waves/SIMD target: VGPR must stay <= 64 (working set ~62, so the bound
// should cost at most a couple of rematerializations, unlike R5's 90->64)
__global__ __launch_bounds__(TPB, 8) void fm_main(
    const int*   __restrict__ idx,      // [8][B]
    const float* __restrict__ label,    // [B][2]
    const float* __restrict__ posw,     // [B][2]
    const float* __restrict__ noise,    // [B][16]
    const float* __restrict__ emb_mean, // [8][12][16]
    const float* __restrict__ emb_std,  // [8][12][16]
    const float* __restrict__ fc_w,     // [28][16]
    const float* __restrict__ emb_act,  // [2][16]
    float*       __restrict__ out,      // [B][2]
    float*       __restrict__ scalar_out, // &out[2B], pre-zeroed via hipMemsetAsync
    float invB, int B)
{
    __shared__ __align__(16) float s_tab[2 * TABSZ];   // mean @0, 0.01*softplus(std) @TABSZ
    __shared__ __align__(16) float s_fcw[NPAIR * EDIM];
    __shared__ __align__(16) float s_ea [2 * EDIM];
    __shared__ float s_red[TPB / 64];

    // ---- stage tables into LDS; softplus folded in once per table entry ----
    for (int t = threadIdx.x; t < NCOLS * ENUM * EDIM; t += TPB) {
        int cv = t >> 4, d = t & 15;
        float m = emb_mean[t];
        float x = emb_std[t];
        float sp = fmaxf(x, 0.0f) + log1pf(expf(-fabsf(x)));   // stable softplus
        s_tab[cv * VPAD + d]         = m;
        s_tab[TABSZ + cv * VPAD + d] = 0.01f * sp;
    }
    for (int t = threadIdx.x; t < NPAIR * EDIM; t += TPB) s_fcw[t] = fc_w[t];
    if (threadIdx.x < 2 * EDIM) s_ea[threadIdx.x] = emb_act[threadIdx.x];
    __syncthreads();

    // dim-split: lane pair (2t, 2t+1) handles one element; h selects dims [8h, 8h+8)
    const int h     = threadIdx.x & 1;
    const int eb    = blockIdx.x * EPB + (threadIdx.x >> 1);
    const int dbase = h * 8;

    // gather bases (idx read redundantly by both halves; coalesces to 128B/wave)
    int base[NCOLS];
    #pragma unroll
    for (int c = 0; c < NCOLS; ++c) {
        int v = idx[(size_t)c * B + eb];
        base[c] = (c * ENUM + v) * VPAD;
    }

    float inf_acc[4] = {0.0f, 0.0f, 0.0f, 0.0f};
    float ad0 = 0.0f, ad1 = 0.0f;

    // this thread covers 8 dims = 2 quarters of 4
    #pragma unroll
    for (int qq = 0; qq < 2; ++qq) {
        const int dq = dbase + qq * 4;

        float nz4[4];
        *reinterpret_cast<float4*>(nz4) =
            *reinterpret_cast<const float4*>(noise + (size_t)eb * EDIM + dq);

        float e[NCOLS][4];
        float cs[4] = {0.0f, 0.0f, 0.0f, 0.0f};

        #pragma unroll
        for (int c = 0; c < NCOLS; ++c) {
            float m[4], sv[4];
            *reinterpret_cast<float4*>(m)  = *reinterpret_cast<const float4*>(&s_tab[base[c] + dq]);
            *reinterpret_cast<float4*>(sv) = *reinterpret_cast<const float4*>(&s_tab[TABSZ + base[c] + dq]);
            #pragma unroll
            for (int k = 0; k < 4; ++k) {
                float ev = fmaf(sv[k], nz4[k], m[k]);
                e[c][k] = ev;
                cs[k] += ev;
            }
        }

        // flat 28 independent pair products (proven R3 dataflow)
        #pragma unroll
        for (int p = 0; p < NPAIR; ++p) {
            const int i = kPI[p], j = kPJ[p];
            float w[4];
            *reinterpret_cast<float4*>(w) = *reinterpret_cast<const float4*>(&s_fcw[p * EDIM + dq]);
            #pragma unroll
            for (int k = 0; k < 4; ++k)
                inf_acc[k] = fmaf(e[i][k] * e[j][k], w[k], inf_acc[k]);
        }

        // action-embedding dots for this quarter
        float ea0[4], ea1[4];
        *reinterpret_cast<float4*>(ea0) = *reinterpret_cast<const float4*>(&s_ea[dq]);
        *reinterpret_cast<float4*>(ea1) = *reinterpret_cast<const float4*>(&s_ea[EDIM + dq]);
        #pragma unroll
        for (int k = 0; k < 4; ++k) {
            ad0 = fmaf(cs[k], ea0[k], ad0);
            ad1 = fmaf(cs[k], ea1[k], ad1);
        }
    }

    // cross-half combine: lane pair (h=0, h=1) sums over all 16 dims
    float inf_s = (inf_acc[0] + inf_acc[1]) + (inf_acc[2] + inf_acc[3]);
    inf_s += __shfl_xor(inf_s, 1);
    ad0   += __shfl_xor(ad0, 1);
    ad1   += __shfl_xor(ad1, 1);

    float lossv = 0.0f;
    if (h == 0) {
        float i0 = inf_s + ad0;
        float i1 = inf_s + ad1;
        float2 lb = reinterpret_cast<const float2*>(label)[eb];
        float2 pw = reinterpret_cast<const float2*>(posw)[eb];
        float d0 = i0 - lb.x;
        float d1 = i1 - lb.y;
        lossv = pw.x * d0 * d0 + pw.y * d1 * d1;
        reinterpret_cast<float2*>(out)[eb] = make_float2(i0, i1);
    }

    // ---- block reduction (h=1 lanes contribute 0), one atomicAdd per block ----
    #pragma unroll
    for (int m = 32; m > 0; m >>= 1) lossv += __shfl_xor(lossv, m);
    const int wid = threadIdx.x >> 6;
    if ((threadIdx.x & 63) == 0) s_red[wid] = lossv;
    __syncthreads();
    if (threadIdx.x == 0) {
        float s = 0.0f;
        #pragma unroll
        for (int w = 0; w < TPB / 64; ++w) s += s_red[w];
        atomicAdd(scalar_out, s * invB);
    }
}

extern "C" void kernel_launch(void* const* d_in, const int* in_sizes, int n_in,
                              void* d_out, int out_size, void* d_ws, size_t ws_size,
                              hipStream_t stream) {
    const int*   idx      = (const int*)d_in[0];
    const float* label    = (const float*)d_in[1];
    const float* posw     = (const float*)d_in[2];
    const float* noise    = (const float*)d_in[3];
    const float* emb_mean = (const float*)d_in[4];
    const float* emb_std  = (const float*)d_in[5];
    const float* fc_w     = (const float*)d_in[6];
    const float* emb_act  = (const float*)d_in[7];
    float* out = (float*)d_out;

    const int B = in_sizes[0] / NCOLS;
    const int blocks = B / EPB;                // 262144 / 128 = 2048, exact
    float* scalar_out = out + (size_t)2 * B;

    hipMemsetAsync(scalar_out, 0, sizeof(float), stream);
    fm_main<<<blocks, TPB, 0, stream>>>(idx, label, posw, noise, emb_mean, emb_std,
                                        fc_w, emb_act, out, scalar_out,
                                        1.0f / (float)B, B);
}

// Round 9
// 48.347 us; speedup vs baseline: 1.7430x; 1.7430x over previous
//
#include <hip/hip_runtime.h>
#include <math.h>

#define NCOLS 8
#define ENUM 12
#define EDIM 16
#define VPAD 20          // padded word stride: (20v+d)%32 spreads banks, <=2-way conflict (free)
#define TABSZ (NCOLS * ENUM * VPAD)
#define NPAIR 28
#define TPB 256

// triu_indices(8, k=1) order
__device__ __constant__ const int kPI[NPAIR] = {0,0,0,0,0,0,0, 1,1,1,1,1,1, 2,2,2,2,2, 3,3,3,3, 4,4,4, 5,5, 6};
__device__ __constant__ const int kPJ[NPAIR] = {1,2,3,4,5,6,7, 2,3,4,5,6,7, 3,4,5,6,7, 4,5,6,7, 5,6,7, 6,7, 7};

// G=1: 1024 blocks -> 4 blocks/CU -> 4 waves/SIMD. NO min-waves bound:
// both times we set it (R5: 4 -> VGPR 64, R8: 8 -> VGPR 32) the compiler
// over-capped VGPRs and spilled to scratch (113-137 MB FETCH, 3-4x slower).
__global__ __launch_bounds__(TPB) void fm_main(
    const int*   __restrict__ idx,      // [8][B]
    const float* __restrict__ label,    // [B][2]
    const float* __restrict__ posw,     // [B][2]
    const float* __restrict__ noise,    // [B][16]
    const float* __restrict__ emb_mean, // [8][12][16]
    const float* __restrict__ emb_std,  // [8][12][16]
    const float* __restrict__ fc_w,     // [28][16]
    const float* __restrict__ emb_act,  // [2][16]
    float*       __restrict__ out,      // [B][2]
    float*       __restrict__ scalar_out, // &out[2B], pre-zeroed via hipMemsetAsync
    float invB, int B)
{
    __shared__ __align__(16) float s_tab[2 * TABSZ];   // mean @0, 0.01*softplus(std) @TABSZ
    __shared__ __align__(16) float s_fcw[NPAIR * EDIM];
    __shared__ __align__(16) float s_ea [2 * EDIM];
    __shared__ float s_red[TPB / 64];

    // ---- stage tables into LDS; softplus folded in once per table entry ----
    for (int t = threadIdx.x; t < NCOLS * ENUM * EDIM; t += TPB) {
        int cv = t >> 4, d = t & 15;
        float m = emb_mean[t];
        float x = emb_std[t];
        float sp = fmaxf(x, 0.0f) + log1pf(expf(-fabsf(x)));   // stable softplus
        s_tab[cv * VPAD + d]         = m;
        s_tab[TABSZ + cv * VPAD + d] = 0.01f * sp;
    }
    for (int t = threadIdx.x; t < NPAIR * EDIM; t += TPB) s_fcw[t] = fc_w[t];
    if (threadIdx.x < 2 * EDIM) s_ea[threadIdx.x] = emb_act[threadIdx.x];
    __syncthreads();

    // exact cover: B = gridDim.x * TPB -> no tail, fully uniform control flow
    const int b = blockIdx.x * TPB + threadIdx.x;

    // issue all global loads up front (idx, noise, label, posw) so their HBM
    // latency overlaps the LDS/VALU compute below
    int base[NCOLS];
    #pragma unroll
    for (int c = 0; c < NCOLS; ++c) {
        int v = idx[(size_t)c * B + b];
        base[c] = (c * ENUM + v) * VPAD;
    }
    float nz[EDIM];
    {
        const float4* np4 = reinterpret_cast<const float4*>(noise + (size_t)b * EDIM);
        float4 a0 = np4[0], a1 = np4[1], a2 = np4[2], a3 = np4[3];
        nz[0]=a0.x; nz[1]=a0.y; nz[2]=a0.z; nz[3]=a0.w;
        nz[4]=a1.x; nz[5]=a1.y; nz[6]=a1.z; nz[7]=a1.w;
        nz[8]=a2.x; nz[9]=a2.y; nz[10]=a2.z; nz[11]=a2.w;
        nz[12]=a3.x; nz[13]=a3.y; nz[14]=a3.z; nz[15]=a3.w;
    }
    float2 lb = reinterpret_cast<const float2*>(label)[b];
    float2 pw = reinterpret_cast<const float2*>(posw)[b];

    // 4 independent fma chains for the pair sum
    float inf_acc[4] = {0.0f, 0.0f, 0.0f, 0.0f};
    float ad0 = 0.0f, ad1 = 0.0f;

    // 4 quarters of d (4 dims each): e[8][4] keeps live registers ~90
    #pragma unroll
    for (int q = 0; q < 4; ++q) {
        float e[NCOLS][4];
        float cs[4] = {0.0f, 0.0f, 0.0f, 0.0f};

        #pragma unroll
        for (int c = 0; c < NCOLS; ++c) {
            float m[4], sv[4];
            *reinterpret_cast<float4*>(m)  = *reinterpret_cast<const float4*>(&s_tab[base[c] + q * 4]);
            *reinterpret_cast<float4*>(sv) = *reinterpret_cast<const float4*>(&s_tab[TABSZ + base[c] + q * 4]);
            #pragma unroll
            for (int k = 0; k < 4; ++k) {
                float ev = fmaf(sv[k], nz[q * 4 + k], m[k]);
                e[c][k] = ev;
                cs[k] += ev;
            }
        }

        // flat 28 independent pair products (proven R3 dataflow)
        #pragma unroll
        for (int p = 0; p < NPAIR; ++p) {
            const int i = kPI[p], j = kPJ[p];
            float w[4];
            *reinterpret_cast<float4*>(w) = *reinterpret_cast<const float4*>(&s_fcw[p * EDIM + q * 4]);
            #pragma unroll
            for (int k = 0; k < 4; ++k)
                inf_acc[k] = fmaf(e[i][k] * e[j][k], w[k], inf_acc[k]);
        }

        // action-embedding dots for this quarter
        float ea0[4], ea1[4];
        *reinterpret_cast<float4*>(ea0) = *reinterpret_cast<const float4*>(&s_ea[q * 4]);
        *reinterpret_cast<float4*>(ea1) = *reinterpret_cast<const float4*>(&s_ea[EDIM + q * 4]);
        #pragma unroll
        for (int k = 0; k < 4; ++k) {
            ad0 = fmaf(cs[k], ea0[k], ad0);
            ad1 = fmaf(cs[k], ea1[k], ad1);
        }
    }

    float inf_s = (inf_acc[0] + inf_acc[1]) + (inf_acc[2] + inf_acc[3]);
    float i0 = inf_s + ad0;
    float i1 = inf_s + ad1;

    float d0 = i0 - lb.x;
    float d1 = i1 - lb.y;
    float lossv = pw.x * d0 * d0 + pw.y * d1 * d1;

    reinterpret_cast<float2*>(out)[b] = make_float2(i0, i1);

    // ---- block reduction, one atomicAdd per block into pre-zeroed slot ----
    #pragma unroll
    for (int m = 32; m > 0; m >>= 1) lossv += __shfl_xor(lossv, m);
    const int wid = threadIdx.x >> 6;
    if ((threadIdx.x & 63) == 0) s_red[wid] = lossv;
    __syncthreads();
    if (threadIdx.x == 0) {
        float s = 0.0f;
        #pragma unroll
        for (int w = 0; w < TPB / 64; ++w) s += s_red[w];
        atomicAdd(scalar_out, s * invB);
    }
}

extern "C" void kernel_launch(void* const* d_in, const int* in_sizes, int n_in,
                              void* d_out, int out_size, void* d_ws, size_t ws_size,
                              hipStream_t stream) {
    const int*   idx      = (const int*)d_in[0];
    const float* label    = (const float*)d_in[1];
    const float* posw     = (const float*)d_in[2];
    const float* noise    = (const float*)d_in[3];
    const float* emb_mean = (const float*)d_in[4];
    const float* emb_std  = (const float*)d_in[5];
    const float* fc_w     = (const float*)d_in[6];
    const float* emb_act  = (const float*)d_in[7];
    float* out = (float*)d_out;

    const int B = in_sizes[0] / NCOLS;
    const int blocks = B / TPB;                // 262144 / 256 = 1024, exact
    float* scalar_out = out + (size_t)2 * B;

    hipMemsetAsync(scalar_out, 0, sizeof(float), stream);
    fm_main<<<blocks, TPB, 0, stream>>>(idx, label, posw, noise, emb_mean, emb_std,
                                        fc_w, emb_act, out, scalar_out,
                                        1.0f / (float)B, B);
}

// Round 10
// 43.315 us; speedup vs baseline: 1.9455x; 1.1162x over previous
//
#include <hip/hip_runtime.h>
#include <math.h>

#define NCOLS 8
#define ENUM 12
#define EDIM 16
#define VPAD 20          // padded word stride: (20v+d)%32 spreads banks, <=2-way conflict (free)
#define TABSZ (NCOLS * ENUM * VPAD)
#define NPAIR 28
#define TPB 256
#define EPB (TPB / 2)    // 2 threads per element (dim-split) -> 128 elems/block, 2048 blocks

// triu_indices(8, k=1) order
__device__ __constant__ const int kPI[NPAIR] = {0,0,0,0,0,0,0, 1,1,1,1,1,1, 2,2,2,2,2, 3,3,3,3, 4,4,4, 5,5, 6};
__device__ __constant__ const int kPJ[NPAIR] = {1,2,3,4,5,6,7, 2,3,4,5,6,7, 3,4,5,6,7, 4,5,6,7, 5,6,7, 6,7, 7};

// Dim-split occupancy experiment, NO min-waves bound (R5/R8 proved it causes
// over-capping + spills). Register pressure held down structurally instead:
// the qq loop stays rolled (#pragma unroll 1) so only one 4-dim slice of the
// working set is live at a time.
__global__ __launch_bounds__(TPB) void fm_main(
    const int*   __restrict__ idx,      // [8][B]
    const float* __restrict__ label,    // [B][2]
    const float* __restrict__ posw,     // [B][2]
    const float* __restrict__ noise,    // [B][16]
    const float* __restrict__ emb_mean, // [8][12][16]
    const float* __restrict__ emb_std,  // [8][12][16]
    const float* __restrict__ fc_w,     // [28][16]
    const float* __restrict__ emb_act,  // [2][16]
    float*       __restrict__ out,      // [B][2]
    float*       __restrict__ scalar_out, // &out[2B], pre-zeroed via hipMemsetAsync
    float invB, int B)
{
    __shared__ __align__(16) float s_tab[2 * TABSZ];   // mean @0, 0.01*softplus(std) @TABSZ
    __shared__ __align__(16) float s_fcw[NPAIR * EDIM];
    __shared__ __align__(16) float s_ea [2 * EDIM];
    __shared__ float s_red[TPB / 64];

    // ---- stage tables into LDS; softplus folded in once per table entry ----
    for (int t = threadIdx.x; t < NCOLS * ENUM * EDIM; t += TPB) {
        int cv = t >> 4, d = t & 15;
        float m = emb_mean[t];
        float x = emb_std[t];
        float sp = fmaxf(x, 0.0f) + log1pf(expf(-fabsf(x)));   // stable softplus
        s_tab[cv * VPAD + d]         = m;
        s_tab[TABSZ + cv * VPAD + d] = 0.01f * sp;
    }
    for (int t = threadIdx.x; t < NPAIR * EDIM; t += TPB) s_fcw[t] = fc_w[t];
    if (threadIdx.x < 2 * EDIM) s_ea[threadIdx.x] = emb_act[threadIdx.x];
    __syncthreads();

    // lane pair (2t, 2t+1) handles one element; h selects dims [8h, 8h+8)
    const int h     = threadIdx.x & 1;
    const int eb    = blockIdx.x * EPB + (threadIdx.x >> 1);
    const int dbase = h * 8;

    // gather bases with dbase folded in (idx read by both halves; coalesces)
    int base[NCOLS];
    #pragma unroll
    for (int c = 0; c < NCOLS; ++c) {
        int v = idx[(size_t)c * B + eb];
        base[c] = (c * ENUM + v) * VPAD + dbase;
    }

    float inf_acc[4] = {0.0f, 0.0f, 0.0f, 0.0f};
    float ad0 = 0.0f, ad1 = 0.0f;

    // rolled: only one 4-dim slice live at a time -> low natural VGPR
    #pragma unroll 1
    for (int qq = 0; qq < 2; ++qq) {
        const int dq = qq * 4;

        float nz4[4];
        *reinterpret_cast<float4*>(nz4) =
            *reinterpret_cast<const float4*>(noise + (size_t)eb * EDIM + dbase + dq);

        float e[NCOLS][4];
        float cs[4] = {0.0f, 0.0f, 0.0f, 0.0f};

        #pragma unroll
        for (int c = 0; c < NCOLS; ++c) {
            float m[4], sv[4];
            *reinterpret_cast<float4*>(m)  = *reinterpret_cast<const float4*>(&s_tab[base[c] + dq]);
            *reinterpret_cast<float4*>(sv) = *reinterpret_cast<const float4*>(&s_tab[TABSZ + base[c] + dq]);
            #pragma unroll
            for (int k = 0; k < 4; ++k) {
                float ev = fmaf(sv[k], nz4[k], m[k]);
                e[c][k] = ev;
                cs[k] += ev;
            }
        }

        // flat 28 independent pair products; w reads are 2-address wave
        // broadcasts (h split) -> 2-way, free
        #pragma unroll
        for (int p = 0; p < NPAIR; ++p) {
            const int i = kPI[p], j = kPJ[p];
            float w[4];
            *reinterpret_cast<float4*>(w) =
                *reinterpret_cast<const float4*>(&s_fcw[p * EDIM + dbase + dq]);
            #pragma unroll
            for (int k = 0; k < 4; ++k)
                inf_acc[k] = fmaf(e[i][k] * e[j][k], w[k], inf_acc[k]);
        }

        float ea0[4], ea1[4];
        *reinterpret_cast<float4*>(ea0) = *reinterpret_cast<const float4*>(&s_ea[dbase + dq]);
        *reinterpret_cast<float4*>(ea1) = *reinterpret_cast<const float4*>(&s_ea[EDIM + dbase + dq]);
        #pragma unroll
        for (int k = 0; k < 4; ++k) {
            ad0 = fmaf(cs[k], ea0[k], ad0);
            ad1 = fmaf(cs[k], ea1[k], ad1);
        }
    }

    // cross-half combine over the lane pair
    float inf_s = (inf_acc[0] + inf_acc[1]) + (inf_acc[2] + inf_acc[3]);
    inf_s += __shfl_xor(inf_s, 1);
    ad0   += __shfl_xor(ad0, 1);
    ad1   += __shfl_xor(ad1, 1);

    float lossv = 0.0f;
    if (h == 0) {
        float i0 = inf_s + ad0;
        float i1 = inf_s + ad1;
        float2 lb = reinterpret_cast<const float2*>(label)[eb];
        float2 pw = reinterpret_cast<const float2*>(posw)[eb];
        float d0 = i0 - lb.x;
        float d1 = i1 - lb.y;
        lossv = pw.x * d0 * d0 + pw.y * d1 * d1;
        reinterpret_cast<float2*>(out)[eb] = make_float2(i0, i1);
    }

    // ---- block reduction (h=1 lanes contribute 0), one atomicAdd per block ----
    #pragma unroll
    for (int m = 32; m > 0; m >>= 1) lossv += __shfl_xor(lossv, m);
    const int wid = threadIdx.x >> 6;
    if ((threadIdx.x & 63) == 0) s_red[wid] = lossv;
    __syncthreads();
    if (threadIdx.x == 0) {
        float s = 0.0f;
        #pragma unroll
        for (int w = 0; w < TPB / 64; ++w) s += s_red[w];
        atomicAdd(scalar_out, s * invB);
    }
}

extern "C" void kernel_launch(void* const* d_in, const int* in_sizes, int n_in,
                              void* d_out, int out_size, void* d_ws, size_t ws_size,
                              hipStream_t stream) {
    const int*   idx      = (const int*)d_in[0];
    const float* label    = (const float*)d_in[1];
    const float* posw     = (const float*)d_in[2];
    const float* noise    = (const float*)d_in[3];
    const float* emb_mean = (const float*)d_in[4];
    const float* emb_std  = (const float*)d_in[5];
    const float* fc_w     = (const float*)d_in[6];
    const float* emb_act  = (const float*)d_in[7];
    float* out = (float*)d_out;

    const int B = in_sizes[0] / NCOLS;
    const int blocks = B / EPB;                // 262144 / 128 = 2048, exact
    float* scalar_out = out + (size_t)2 * B;

    hipMemsetAsync(scalar_out, 0, sizeof(float), stream);
    fm_main<<<blocks, TPB, 0, stream>>>(idx, label, posw, noise, emb_mean, emb_std,
                                        fc_w, emb_act, out, scalar_out,
                                        1.0f / (float)B, B);
}